// Round 12
// baseline (433.390 us; speedup 1.0000x reference)
//
#include <hip/hip_runtime.h>

// MoE-INR fused megakernel, bf16 MFMA (gfx950).
// Round 16: tile-per-wave-group. r15 (248us) cycle model: LDS read port is
// the largest consumer (~88us/CU: 1104 ds_read_b128/wave x 16 wave-blocks x
// 12cyc; all 8 waves read IDENTICAL A-frags = 8x duplication) > VALU 71 >
// MFMA 58. Fix: waves 0-3 -> tile 0, waves 4-7 -> tile 1, each wave 64 rows
// x 64 cols (NPW=4, 16 MFMA/k0). A-duplication 8x->4x (port ~88->50us).
// W cols loaded once per wave-GROUP (2x instrs/block, second hits L1: per-k0
// W working set 16KB < 32KB L1); MFMA:b-load stays 4:1 (r12's fatal config
// was 2:1 -- that, not duplication per se, was its failure).
// Kept: sin_rev + KSIN pre-scale (r9/r11), manual-RNE pack (r8 lesson),
// register-light gate (r6), dual 64-row tiles 1 blk/CU (r13), (512,2)
// launch bounds (256-VGPR budget, reg model r7-r10), convert grid 1024.

typedef short v8s __attribute__((ext_vector_type(8)));
typedef float v4f __attribute__((ext_vector_type(4)));

#define KSIN 4.774648293f   // 30/(2*pi): sine-layer scale, folded into weights
#define AST 264             // LDS row stride in bf16 elements (16B-aligned rows)
#define PST 9               // probs row stride (floats)
#define N_CVT 8

__device__ __forceinline__ float bf2f(unsigned short h) {
  union { unsigned u; float f; } v; v.u = ((unsigned)h) << 16; return v.f;
}
__device__ __forceinline__ unsigned short f2bf(float f) {
  union { float f; unsigned u; } v; v.f = f;
  unsigned r = v.u + 0x7fffu + ((v.u >> 16) & 1u);  // RNE
  return (unsigned short)(r >> 16);
}
__device__ __forceinline__ unsigned pack2(float a, float b) {
  return (unsigned)f2bf(a) | ((unsigned)f2bf(b) << 16);  // manual RNE (verified)
}
__device__ __forceinline__ float sin_rev(float x) {  // sin(2*pi*x)
  return __builtin_amdgcn_sinf(x);
}
__device__ __forceinline__ float cos_rev(float x) {  // cos(2*pi*x)
  return __builtin_amdgcn_cosf(x);
}

struct CvtArgs {
  const float* src[N_CVT];
  unsigned     off[N_CVT];
  unsigned     n[N_CVT];
  float        scl[N_CVT];   // KSIN for sine-layer weights, 1.0 otherwise
};

__global__ void convert_kernel(CvtArgs a, unsigned short* __restrict__ dst) {
  const int tid = blockIdx.x * blockDim.x + threadIdx.x;
  const int stride = gridDim.x * blockDim.x;
  for (int k = 0; k < N_CVT; k++) {
    const unsigned n4 = a.n[k] >> 2;
    const float4* s = (const float4*)a.src[k];
    const float sc = a.scl[k];
    uint2* d = (uint2*)(dst + a.off[k]);
    for (unsigned i = tid; i < n4; i += stride) {
      float4 v = s[i];
      uint2 o; o.x = pack2(v.x * sc, v.y * sc); o.y = pack2(v.z * sc, v.w * sc);
      d[i] = o;
    }
    for (unsigned i = (n4 << 2) + tid; i < a.n[k]; i += stride)
      dst[a.off[k] + i] = f2bf(a.src[k][i] * sc);
  }
}

// -------- tile-per-wave-group GEMM: waves 0-3 tile0, waves 4-7 tile1 ------
// Wave (tl = wave>>2, wl = wave&3) computes
//   O{tl}[0:64, oc + wl*NPW*16 : +NPW*16] from A{tl}.
// A-frags read from ONE tile only (4x duplication across waves, not 8x).
// Swapped operands: lane holds D[wcol=q*4+r][act_row=m15]; packed 8B stores.
// ACT: 0 = sin(2pi*(z + KSIN*b)) [W pre-scaled], 1 = relu, 2 = relu(z+skip)
template<int K, int NPW, int ACT>
__device__ __forceinline__ void wgemm1(const unsigned short* A0,
                                       const unsigned short* A1,
                                       unsigned short* O0, unsigned short* O1,
                                       int oc,
                                       const unsigned short* __restrict__ W,
                                       const float* __restrict__ bias,
                                       const unsigned short* skip0,
                                       const unsigned short* skip1) {
  const int lane = threadIdx.x & 63;
  const int wave = threadIdx.x >> 6;
  const int tl   = wave >> 2;
  const int wl   = wave & 3;
  const int m15  = lane & 15;
  const int q    = lane >> 4;
  const int n0   = wl * (NPW * 16);
  const unsigned short* A   = tl ? A1 : A0;
  unsigned short*       OUT = tl ? O1 : O0;
  const unsigned short* skp = tl ? skip1 : skip0;
  v4f acc[NPW][4];
#pragma unroll
  for (int i = 0; i < NPW; i++)
#pragma unroll
    for (int j = 0; j < 4; j++) acc[i][j] = (v4f){0.f, 0.f, 0.f, 0.f};

#pragma unroll
  for (int k0 = 0; k0 < K / 32; ++k0) {
    v8s a[4], b[NPW];
#pragma unroll
    for (int ct = 0; ct < NPW; ct++)
      b[ct] = *(const v8s*)(W + (size_t)(n0 + ct * 16 + m15) * K + k0 * 32 + q * 8);
#pragma unroll
    for (int rt = 0; rt < 4; rt++)
      a[rt] = *(const v8s*)(A + (rt * 16 + m15) * AST + k0 * 32 + q * 8);
#pragma unroll
    for (int ct = 0; ct < NPW; ct++)
#pragma unroll
      for (int rt = 0; rt < 4; rt++)
        acc[ct][rt] = __builtin_amdgcn_mfma_f32_16x16x32_bf16(b[ct], a[rt], acc[ct][rt], 0, 0, 0);
  }

#pragma unroll
  for (int ct = 0; ct < NPW; ct++) {
    const int c0 = n0 + ct * 16 + q * 4;
    v4f bv = *(const v4f*)(bias + c0);
    if (ACT == 0) bv *= KSIN;
#pragma unroll
    for (int rt = 0; rt < 4; rt++) {
      const int row = rt * 16 + m15;
      const v4f av = acc[ct][rt];
      float o0, o1, o2, o3;
      if (ACT == 2) {
        const uint2 sk = *(const uint2*)(skp + row * AST + c0);
        o0 = fmaxf(av[0] + bv[0] + bf2f((unsigned short)(sk.x & 0xffffu)), 0.f);
        o1 = fmaxf(av[1] + bv[1] + bf2f((unsigned short)(sk.x >> 16)), 0.f);
        o2 = fmaxf(av[2] + bv[2] + bf2f((unsigned short)(sk.y & 0xffffu)), 0.f);
        o3 = fmaxf(av[3] + bv[3] + bf2f((unsigned short)(sk.y >> 16)), 0.f);
      } else if (ACT == 1) {
        o0 = fmaxf(av[0] + bv[0], 0.f);
        o1 = fmaxf(av[1] + bv[1], 0.f);
        o2 = fmaxf(av[2] + bv[2], 0.f);
        o3 = fmaxf(av[3] + bv[3], 0.f);
      } else {
        o0 = sin_rev(av[0] + bv[0]);
        o1 = sin_rev(av[1] + bv[1]);
        o2 = sin_rev(av[2] + bv[2]);
        o3 = sin_rev(av[3] + bv[3]);
      }
      uint2 w2; w2.x = pack2(o0, o1); w2.y = pack2(o2, o3);
      *(uint2*)(OUT + row * AST + oc + c0) = w2;
    }
  }
}

// Expert layer 2 (sine, W pre-scaled) + final 256->1 dot, tile-per-group.
// Wave (tl, wl) covers its tile's 64 rows x 64 cols (n0 = wl*64, 4 ct).
// Per-row partials -> pp[tl*256 + wl*64 + row] (no atomics).
__device__ __forceinline__ void wexpert2s(const unsigned short* A0,
                                          const unsigned short* A1,
                                          const unsigned short* __restrict__ W,
                                          const float* __restrict__ bias,
                                          const float* __restrict__ wfin,
                                          float* __restrict__ pp) {
  const int lane = threadIdx.x & 63;
  const int wave = threadIdx.x >> 6;
  const int tl   = wave >> 2;
  const int wl   = wave & 3;
  const int m15  = lane & 15;
  const int q    = lane >> 4;
  const int n0   = wl * 64;
  const unsigned short* A = tl ? A1 : A0;
  v4f acc[4][4];
#pragma unroll
  for (int i = 0; i < 4; i++)
#pragma unroll
    for (int j = 0; j < 4; j++) acc[i][j] = (v4f){0.f, 0.f, 0.f, 0.f};

#pragma unroll
  for (int k0 = 0; k0 < 8; ++k0) {
    v8s a[4], b[4];
#pragma unroll
    for (int ct = 0; ct < 4; ct++)
      b[ct] = *(const v8s*)(W + (size_t)(n0 + ct * 16 + m15) * 256 + k0 * 32 + q * 8);
#pragma unroll
    for (int rt = 0; rt < 4; rt++)
      a[rt] = *(const v8s*)(A + (rt * 16 + m15) * AST + k0 * 32 + q * 8);
#pragma unroll
    for (int ct = 0; ct < 4; ct++)
#pragma unroll
      for (int rt = 0; rt < 4; rt++)
        acc[ct][rt] = __builtin_amdgcn_mfma_f32_16x16x32_bf16(b[ct], a[rt], acc[ct][rt], 0, 0, 0);
  }

  float p[4] = {0.f, 0.f, 0.f, 0.f};
#pragma unroll
  for (int ct = 0; ct < 4; ct++) {
    const int c0 = n0 + ct * 16 + q * 4;
    v4f bv = *(const v4f*)(bias + c0);
    bv *= KSIN;
    const v4f wf = *(const v4f*)(wfin + c0);
#pragma unroll
    for (int rt = 0; rt < 4; rt++)
#pragma unroll
      for (int r = 0; r < 4; r++)
        p[rt] += sin_rev(acc[ct][rt][r] + bv[r]) * wf[r];
  }
  // reduce over q (lanes 16 apart hold same act_row, different cols)
#pragma unroll
  for (int rt = 0; rt < 4; rt++) {
    float v = p[rt];
    v += __shfl_xor(v, 16);
    v += __shfl_xor(v, 32);
    if (q == 0) pp[tl * 256 + wl * 64 + rt * 16 + m15] = v;
  }
}

__global__ __launch_bounds__(512, 2) void moe_inr_kernel(
    const float* __restrict__ x,
    const unsigned short* __restrict__ es1w, const float* __restrict__ es1b,
    const unsigned short* __restrict__ es2w, const float* __restrict__ es2b,
    const unsigned short* __restrict__ rf1w, const float* __restrict__ rf1b,
    const unsigned short* __restrict__ rf2w, const float* __restrict__ rf2b,
    const unsigned short* __restrict__ rf3w, const float* __restrict__ rf3b,
    const float* __restrict__ ps1w,          const float* __restrict__ ps1b,
    const unsigned short* __restrict__ ps2w, const float* __restrict__ ps2b,
    const float* __restrict__ gw,            const float* __restrict__ gb,
    const unsigned short* __restrict__ xs1w, const float* __restrict__ xs1b,
    const unsigned short* __restrict__ xs2w, const float* __restrict__ xs2b,
    const float* __restrict__ xfw,           const float* __restrict__ xfb,
    float* __restrict__ out) {
  __shared__ __align__(16) unsigned short P[2][64 * AST];
  __shared__ __align__(16) unsigned short Q[2][64 * AST];
  __shared__ float probs[2][64 * PST];
  __shared__ float pred_part[2 * 4 * 64];

  const int t   = threadIdx.x;
  const int r0g = blockIdx.x * 128;   // two 64-row tiles

  // Stage 0: positional encoding -> P[tl] cols [0,64), both tiles.
#pragma unroll
  for (int tl = 0; tl < 2; ++tl) {
    const int row = t & 63, g = t >> 6, c = g & 3, jh = g >> 2;
    const float xv = x[(r0g + tl * 64 + row) * 4 + c];
    float sn[4], cs[4];
#pragma unroll
    for (int jj = 0; jj < 4; jj++) {
      const int j = jh * 4 + jj;
      const float rev = xv * (0.5f * (float)(1 << j));
      sn[jj] = sin_rev(rev);
      cs[jj] = cos_rev(rev);
    }
    uint2 ws; ws.x = pack2(sn[0], sn[1]); ws.y = pack2(sn[2], sn[3]);
    uint2 wc2; wc2.x = pack2(cs[0], cs[1]); wc2.y = pack2(cs[2], cs[3]);
    *(uint2*)(P[tl] + row * AST + c * 16 + jh * 4) = ws;
    *(uint2*)(P[tl] + row * AST + c * 16 + 8 + jh * 4) = wc2;
  }
  __syncthreads();
  wgemm1<64, 2, 0>(P[0], P[1], P[0], P[1], 64, es1w, es1b, nullptr, nullptr);
  __syncthreads();
  wgemm1<128, 4, 0>(P[0] + 64, P[1] + 64, Q[0], Q[1], 0, es2w, es2b, nullptr, nullptr);
  __syncthreads();
  wgemm1<256, 2, 1>(Q[0], Q[1], P[0], P[1], 0, rf1w, rf1b, nullptr, nullptr);
  __syncthreads();
  wgemm1<128, 2, 1>(P[0], P[1], P[0], P[1], 128, rf2w, rf2b, nullptr, nullptr);
  __syncthreads();
  wgemm1<128, 4, 2>(P[0] + 128, P[1] + 128, Q[0], Q[1], 0, rf3w, rf3b, Q[0], Q[1]);
  __syncthreads();
  // pol_s1 (K=4) in f32: pf1 -> P[tl][0,128). 16 outputs/thread/tile.
#pragma unroll
  for (int tl = 0; tl < 2; ++tl) {
    const int row = t & 63, g = t >> 6;
    const v4f xv = *(const v4f*)(x + (r0g + tl * 64 + row) * 4);
#pragma unroll
    for (int ii = 0; ii < 4; ii++) {
      float oo[4];
#pragma unroll
      for (int i2 = 0; i2 < 4; i2++) {
        const int o = g * 16 + ii * 4 + i2;
        const v4f w4 = *(const v4f*)(ps1w + o * 4);
        const float z = xv[0] * w4[0] + xv[1] * w4[1] + xv[2] * w4[2] +
                        xv[3] * w4[3] + ps1b[o];
        oo[i2] = sin_rev(KSIN * z);
      }
      uint2 w2; w2.x = pack2(oo[0], oo[1]); w2.y = pack2(oo[2], oo[3]);
      *(uint2*)(P[tl] + row * AST + g * 16 + ii * 4) = w2;
    }
  }
  __syncthreads();
  wgemm1<128, 2, 0>(P[0], P[1], P[0], P[1], 128, ps2w, ps2b, nullptr, nullptr);
  __syncthreads();
  // gate (f32 weights): per tile, 8 partial-threads per row, 48 k each.
#pragma unroll
  for (int tl = 0; tl < 2; ++tl) {
    const int row = t >> 3, pp = t & 7;
    float lg[7] = {0.f, 0.f, 0.f, 0.f, 0.f, 0.f, 0.f};
#pragma unroll
    for (int u = 0; u < 6; u++) {
      const int kk = pp * 48 + u * 8;
      const v8s av = (kk < 256) ? *(const v8s*)(Q[tl] + row * AST + kk)
                                : *(const v8s*)(P[tl] + row * AST + 128 + (kk - 256));
      float af[8];
#pragma unroll
      for (int e2 = 0; e2 < 8; e2++) af[e2] = bf2f((unsigned short)av[e2]);
#pragma unroll
      for (int j = 0; j < 7; j++) {
        const v4f g0 = *(const v4f*)(gw + j * 384 + kk);
        const v4f g1 = *(const v4f*)(gw + j * 384 + kk + 4);
        lg[j] += af[0] * g0[0] + af[1] * g0[1] + af[2] * g0[2] + af[3] * g0[3] +
                 af[4] * g1[0] + af[5] * g1[1] + af[6] * g1[2] + af[7] * g1[3];
      }
    }
#pragma unroll
    for (int j = 0; j < 7; j++) {
      float s = lg[j];
      s += __shfl_xor(s, 1);
      s += __shfl_xor(s, 2);
      s += __shfl_xor(s, 4);
      lg[j] = s;
    }
    if (pp == 0) {
#pragma unroll
      for (int j = 0; j < 7; j++) probs[tl][row * PST + j] = lg[j] + gb[j];
    }
  }
  __syncthreads();
  float yr = 0.f;
  if (t < 128) {  // softmax over 7, tile = t>>6, row = t&63
    const int tl = t >> 6, row = t & 63;
    float m = probs[tl][row * PST];
#pragma unroll
    for (int j = 1; j < 7; j++) m = fmaxf(m, probs[tl][row * PST + j]);
    float s = 0.f, e[7];
#pragma unroll
    for (int j = 0; j < 7; j++) { e[j] = __expf(probs[tl][row * PST + j] - m); s += e[j]; }
    const float inv = 1.f / s;
#pragma unroll
    for (int j = 0; j < 7; j++) probs[tl][row * PST + j] = e[j] * inv;
  }
  // experts: enc_feat stays in Q[tl]; e1 -> P[tl]; e2+final fused in regs.
  for (int ex = 0; ex < 7; ++ex) {
    wgemm1<256, 4, 0>(Q[0], Q[1], P[0], P[1], 0,
                      xs1w + ex * 65536, xs1b + ex * 256, nullptr, nullptr);
    __syncthreads();
    wexpert2s(P[0], P[1], xs2w + ex * 65536, xs2b + ex * 256, xfw + ex * 256,
              pred_part);
    __syncthreads();
    if (t < 128) {
      const int tl = t >> 6, row = t & 63;
      float pr = pred_part[tl * 256 + row] + pred_part[tl * 256 + 64 + row] +
                 pred_part[tl * 256 + 128 + row] + pred_part[tl * 256 + 192 + row];
      yr += (pr + xfb[ex]) * probs[tl][row * PST + ex];
    }
  }
  if (t < 128) out[r0g + t] = yr;
}

extern "C" void kernel_launch(void* const* d_in, const int* in_sizes, int n_in,
                              void* d_out, int out_size, void* d_ws, size_t ws_size,
                              hipStream_t stream) {
  (void)out_size; (void)n_in; (void)ws_size;
  const int   idx[N_CVT] = {1, 3, 5, 7, 9, 13, 17, 19};
  // KSIN folded into sine-layer weights (enc_s1, enc_s2, pol_s2, exp_s1, exp_s2)
  const float scl[N_CVT] = {KSIN, KSIN, 1.f, 1.f, 1.f, KSIN, KSIN, KSIN};
  unsigned off[N_CVT], cur = 0;
  CvtArgs a;
  for (int i = 0; i < N_CVT; i++) {
    off[i] = cur;
    a.src[i] = (const float*)d_in[idx[i]];
    a.off[i] = cur;
    a.n[i]   = (unsigned)in_sizes[idx[i]];
    a.scl[i] = scl[i];
    cur += ((unsigned)in_sizes[idx[i]] + 7u) & ~7u;  // 16B-align each array
  }
  unsigned short* dst = (unsigned short*)d_ws;
  hipLaunchKernelGGL(convert_kernel, dim3(1024), dim3(256), 0, stream, a, dst);
  hipLaunchKernelGGL(moe_inr_kernel, dim3(65536 / 128), dim3(512), 0, stream,
      (const float*)d_in[0],
      dst + off[0], (const float*)d_in[2],
      dst + off[1], (const float*)d_in[4],
      dst + off[2], (const float*)d_in[6],
      dst + off[3], (const float*)d_in[8],
      dst + off[4], (const float*)d_in[10],
      (const float*)d_in[11], (const float*)d_in[12],
      dst + off[5], (const float*)d_in[14],
      (const float*)d_in[15], (const float*)d_in[16],
      dst + off[6], (const float*)d_in[18],
      dst + off[7], (const float*)d_in[20],
      (const float*)d_in[21], (const float*)d_in[22],
      (float*)d_out);
}

// Round 13
// 329.790 us; speedup vs baseline: 1.3141x; 1.3141x over previous
//
#include <hip/hip_runtime.h>

// MoE-INR fused megakernel, bf16 MFMA (gfx950).
// Round 17: r15 base (248us best) + Q-register-cache (k0<2) for expert e1.
// r16 verdict: per-wave GLOBAL b-load count is the dominant lever (248/271/
// 357/578us at 1/2/2/4 b-loads per 16 MFMA); r15 is at the b-instruction
// floor (zero duplication). Remaining budget: LDS port ~88us (8x A-read
// duplication across waves) > VALU 71 > MFMA 58, ~13% stall. Only A-cut that
// adds no b-loads: cache Q (e1's A operand, constant across all 7 experts)
// in registers. k0<2 hoist = 16 v8s = 64 VGPR; saves 112 a-reads/wave.
// Unlike r9/r10's failed hoist: we are LDS-capped at 1 blk/CU under (512,2)
// with 128/256 VGPR used -> hoist registers are free (no spill, no eviction).
// Kept: fused dual-tile wgemm2 (r15), 1x8 wave grid (r12), sin_rev + KSIN
// pre-scale (r9/r11), manual-RNE pack (r8), register-light gate (r6),
// atomic-free expert partials, convert grid 1024.

typedef short v8s __attribute__((ext_vector_type(8)));
typedef float v4f __attribute__((ext_vector_type(4)));

#define KSIN 4.774648293f   // 30/(2*pi): sine-layer scale, folded into weights
#define AST 264             // LDS row stride in bf16 elements (16B-aligned rows)
#define PST 9               // probs row stride (floats)
#define N_CVT 8

__device__ __forceinline__ float bf2f(unsigned short h) {
  union { unsigned u; float f; } v; v.u = ((unsigned)h) << 16; return v.f;
}
__device__ __forceinline__ unsigned short f2bf(float f) {
  union { float f; unsigned u; } v; v.f = f;
  unsigned r = v.u + 0x7fffu + ((v.u >> 16) & 1u);  // RNE
  return (unsigned short)(r >> 16);
}
__device__ __forceinline__ unsigned pack2(float a, float b) {
  return (unsigned)f2bf(a) | ((unsigned)f2bf(b) << 16);  // manual RNE (verified)
}
__device__ __forceinline__ float sin_rev(float x) {  // sin(2*pi*x)
  return __builtin_amdgcn_sinf(x);
}
__device__ __forceinline__ float cos_rev(float x) {  // cos(2*pi*x)
  return __builtin_amdgcn_cosf(x);
}

struct CvtArgs {
  const float* src[N_CVT];
  unsigned     off[N_CVT];
  unsigned     n[N_CVT];
  float        scl[N_CVT];   // KSIN for sine-layer weights, 1.0 otherwise
};

__global__ void convert_kernel(CvtArgs a, unsigned short* __restrict__ dst) {
  const int tid = blockIdx.x * blockDim.x + threadIdx.x;
  const int stride = gridDim.x * blockDim.x;
  for (int k = 0; k < N_CVT; k++) {
    const unsigned n4 = a.n[k] >> 2;
    const float4* s = (const float4*)a.src[k];
    const float sc = a.scl[k];
    uint2* d = (uint2*)(dst + a.off[k]);
    for (unsigned i = tid; i < n4; i += stride) {
      float4 v = s[i];
      uint2 o; o.x = pack2(v.x * sc, v.y * sc); o.y = pack2(v.z * sc, v.w * sc);
      d[i] = o;
    }
    for (unsigned i = (n4 << 2) + tid; i < a.n[k]; i += stride)
      dst[a.off[k] + i] = f2bf(a.src[k][i] * sc);
  }
}

// ------------- fused dual-tile wave GEMM, 1x8 wave grid, RT=4 -------------
// Wave w computes O{0,1}[0:64, oc + w*NPW*16 : +NPW*16] for both tiles.
// b[ct] loaded ONCE per k0, feeds both tiles' MFMAs (16 per k0 at NPW=2).
// Swapped operands: lane holds D[wcol=q*4+r][act_row=m15]; packed 8B stores.
// ACT: 0 = sin(2pi*(z + KSIN*b)) [W pre-scaled], 1 = relu, 2 = relu(z+skip)
template<int K, int NPW, int ACT>
__device__ __forceinline__ void wgemm2(const unsigned short* A0,
                                       const unsigned short* A1,
                                       unsigned short* O0, unsigned short* O1,
                                       int oc,
                                       const unsigned short* __restrict__ W,
                                       const float* __restrict__ bias,
                                       const unsigned short* skip0,
                                       const unsigned short* skip1) {
  const int lane = threadIdx.x & 63;
  const int wave = threadIdx.x >> 6;
  const int m15  = lane & 15;
  const int q    = lane >> 4;
  const int n0   = wave * (NPW * 16);
  v4f acc[2][NPW][4];
#pragma unroll
  for (int tl = 0; tl < 2; tl++)
#pragma unroll
    for (int i = 0; i < NPW; i++)
#pragma unroll
      for (int j = 0; j < 4; j++) acc[tl][i][j] = (v4f){0.f, 0.f, 0.f, 0.f};

#pragma unroll
  for (int k0 = 0; k0 < K / 32; ++k0) {
    v8s b[NPW], a0[4], a1[4];
#pragma unroll
    for (int ct = 0; ct < NPW; ct++)
      b[ct] = *(const v8s*)(W + (size_t)(n0 + ct * 16 + m15) * K + k0 * 32 + q * 8);
#pragma unroll
    for (int rt = 0; rt < 4; rt++) {
      a0[rt] = *(const v8s*)(A0 + (rt * 16 + m15) * AST + k0 * 32 + q * 8);
      a1[rt] = *(const v8s*)(A1 + (rt * 16 + m15) * AST + k0 * 32 + q * 8);
    }
#pragma unroll
    for (int ct = 0; ct < NPW; ct++)
#pragma unroll
      for (int rt = 0; rt < 4; rt++) {
        acc[0][ct][rt] = __builtin_amdgcn_mfma_f32_16x16x32_bf16(b[ct], a0[rt], acc[0][ct][rt], 0, 0, 0);
        acc[1][ct][rt] = __builtin_amdgcn_mfma_f32_16x16x32_bf16(b[ct], a1[rt], acc[1][ct][rt], 0, 0, 0);
      }
  }

#pragma unroll
  for (int ct = 0; ct < NPW; ct++) {
    const int c0 = n0 + ct * 16 + q * 4;
    v4f bv = *(const v4f*)(bias + c0);
    if (ACT == 0) bv *= KSIN;
#pragma unroll
    for (int rt = 0; rt < 4; rt++) {
      const int row = rt * 16 + m15;
#pragma unroll
      for (int tl = 0; tl < 2; tl++) {
        const v4f av = acc[tl][ct][rt];
        unsigned short* OUT = tl ? O1 : O0;
        const unsigned short* skip = tl ? skip1 : skip0;
        float o0, o1, o2, o3;
        if (ACT == 2) {
          const uint2 sk = *(const uint2*)(skip + row * AST + c0);
          o0 = fmaxf(av[0] + bv[0] + bf2f((unsigned short)(sk.x & 0xffffu)), 0.f);
          o1 = fmaxf(av[1] + bv[1] + bf2f((unsigned short)(sk.x >> 16)), 0.f);
          o2 = fmaxf(av[2] + bv[2] + bf2f((unsigned short)(sk.y & 0xffffu)), 0.f);
          o3 = fmaxf(av[3] + bv[3] + bf2f((unsigned short)(sk.y >> 16)), 0.f);
        } else if (ACT == 1) {
          o0 = fmaxf(av[0] + bv[0], 0.f);
          o1 = fmaxf(av[1] + bv[1], 0.f);
          o2 = fmaxf(av[2] + bv[2], 0.f);
          o3 = fmaxf(av[3] + bv[3], 0.f);
        } else {
          o0 = sin_rev(av[0] + bv[0]);
          o1 = sin_rev(av[1] + bv[1]);
          o2 = sin_rev(av[2] + bv[2]);
          o3 = sin_rev(av[3] + bv[3]);
        }
        uint2 w2; w2.x = pack2(o0, o1); w2.y = pack2(o2, o3);
        *(uint2*)(OUT + row * AST + oc + c0) = w2;
      }
    }
  }
}

// Expert e1 (K=256, NPW=2, sine) with k0<2 A-frags from registers (qh),
// k0>=2 from LDS. qh[tl][k0][rt]: enc_feat is constant across all 7 experts.
__device__ __forceinline__ void wgemm2q(const unsigned short* A0,
                                        const unsigned short* A1,
                                        unsigned short* O0, unsigned short* O1,
                                        const v8s (&qh)[2][2][4],
                                        const unsigned short* __restrict__ W,
                                        const float* __restrict__ bias) {
  const int lane = threadIdx.x & 63;
  const int wave = threadIdx.x >> 6;
  const int m15  = lane & 15;
  const int q    = lane >> 4;
  const int n0   = wave * 32;
  v4f acc[2][2][4];
#pragma unroll
  for (int tl = 0; tl < 2; tl++)
#pragma unroll
    for (int i = 0; i < 2; i++)
#pragma unroll
      for (int j = 0; j < 4; j++) acc[tl][i][j] = (v4f){0.f, 0.f, 0.f, 0.f};

#pragma unroll
  for (int k0 = 0; k0 < 8; ++k0) {
    v8s b[2], a0[4], a1[4];
#pragma unroll
    for (int ct = 0; ct < 2; ct++)
      b[ct] = *(const v8s*)(W + (size_t)(n0 + ct * 16 + m15) * 256 + k0 * 32 + q * 8);
#pragma unroll
    for (int rt = 0; rt < 4; rt++) {
      if (k0 < 2) {
        a0[rt] = qh[0][k0][rt];
        a1[rt] = qh[1][k0][rt];
      } else {
        a0[rt] = *(const v8s*)(A0 + (rt * 16 + m15) * AST + k0 * 32 + q * 8);
        a1[rt] = *(const v8s*)(A1 + (rt * 16 + m15) * AST + k0 * 32 + q * 8);
      }
    }
#pragma unroll
    for (int ct = 0; ct < 2; ct++)
#pragma unroll
      for (int rt = 0; rt < 4; rt++) {
        acc[0][ct][rt] = __builtin_amdgcn_mfma_f32_16x16x32_bf16(b[ct], a0[rt], acc[0][ct][rt], 0, 0, 0);
        acc[1][ct][rt] = __builtin_amdgcn_mfma_f32_16x16x32_bf16(b[ct], a1[rt], acc[1][ct][rt], 0, 0, 0);
      }
  }

#pragma unroll
  for (int ct = 0; ct < 2; ct++) {
    const int c0 = n0 + ct * 16 + q * 4;
    v4f bv = *(const v4f*)(bias + c0);
    bv *= KSIN;
#pragma unroll
    for (int rt = 0; rt < 4; rt++) {
      const int row = rt * 16 + m15;
#pragma unroll
      for (int tl = 0; tl < 2; tl++) {
        const v4f av = acc[tl][ct][rt];
        unsigned short* OUT = tl ? O1 : O0;
        float o0 = sin_rev(av[0] + bv[0]);
        float o1 = sin_rev(av[1] + bv[1]);
        float o2 = sin_rev(av[2] + bv[2]);
        float o3 = sin_rev(av[3] + bv[3]);
        uint2 w2; w2.x = pack2(o0, o1); w2.y = pack2(o2, o3);
        *(uint2*)(OUT + row * AST + c0) = w2;
      }
    }
  }
}

// Fused dual-tile expert layer 2 (sine, W pre-scaled) + final 256->1 dot.
// Wave owns 32 unique cols; b loaded once per k0 for both tiles.
// Per-row partial sums -> pp{0,1}[wave][row] (no atomics).
__device__ __forceinline__ void wexpert2d(const unsigned short* A0,
                                          const unsigned short* A1,
                                          const unsigned short* __restrict__ W,
                                          const float* __restrict__ bias,
                                          const float* __restrict__ wfin,
                                          float* __restrict__ pp0,
                                          float* __restrict__ pp1) {
  const int lane = threadIdx.x & 63;
  const int wave = threadIdx.x >> 6;
  const int m15  = lane & 15;
  const int q    = lane >> 4;
  const int n0   = wave * 32;
  v4f acc[2][2][4];
#pragma unroll
  for (int tl = 0; tl < 2; tl++)
#pragma unroll
    for (int i = 0; i < 2; i++)
#pragma unroll
      for (int j = 0; j < 4; j++) acc[tl][i][j] = (v4f){0.f, 0.f, 0.f, 0.f};

#pragma unroll
  for (int k0 = 0; k0 < 8; ++k0) {
    v8s b[2], a0[4], a1[4];
#pragma unroll
    for (int ct = 0; ct < 2; ct++)
      b[ct] = *(const v8s*)(W + (size_t)(n0 + ct * 16 + m15) * 256 + k0 * 32 + q * 8);
#pragma unroll
    for (int rt = 0; rt < 4; rt++) {
      a0[rt] = *(const v8s*)(A0 + (rt * 16 + m15) * AST + k0 * 32 + q * 8);
      a1[rt] = *(const v8s*)(A1 + (rt * 16 + m15) * AST + k0 * 32 + q * 8);
    }
#pragma unroll
    for (int ct = 0; ct < 2; ct++)
#pragma unroll
      for (int rt = 0; rt < 4; rt++) {
        acc[0][ct][rt] = __builtin_amdgcn_mfma_f32_16x16x32_bf16(b[ct], a0[rt], acc[0][ct][rt], 0, 0, 0);
        acc[1][ct][rt] = __builtin_amdgcn_mfma_f32_16x16x32_bf16(b[ct], a1[rt], acc[1][ct][rt], 0, 0, 0);
      }
  }

  float p0[4] = {0.f, 0.f, 0.f, 0.f};
  float p1[4] = {0.f, 0.f, 0.f, 0.f};
#pragma unroll
  for (int ct = 0; ct < 2; ct++) {
    const int c0 = n0 + ct * 16 + q * 4;
    v4f bv = *(const v4f*)(bias + c0);
    bv *= KSIN;
    const v4f wf = *(const v4f*)(wfin + c0);
#pragma unroll
    for (int rt = 0; rt < 4; rt++)
#pragma unroll
      for (int r = 0; r < 4; r++) {
        p0[rt] += sin_rev(acc[0][ct][rt][r] + bv[r]) * wf[r];
        p1[rt] += sin_rev(acc[1][ct][rt][r] + bv[r]) * wf[r];
      }
  }
  // reduce over q (lanes 16 apart hold same act_row, different cols)
#pragma unroll
  for (int rt = 0; rt < 4; rt++) {
    float v0 = p0[rt], v1 = p1[rt];
    v0 += __shfl_xor(v0, 16);
    v0 += __shfl_xor(v0, 32);
    v1 += __shfl_xor(v1, 16);
    v1 += __shfl_xor(v1, 32);
    if (q == 0) {
      pp0[wave * 64 + rt * 16 + m15] = v0;
      pp1[wave * 64 + rt * 16 + m15] = v1;
    }
  }
}

__global__ __launch_bounds__(512, 2) void moe_inr_kernel(
    const float* __restrict__ x,
    const unsigned short* __restrict__ es1w, const float* __restrict__ es1b,
    const unsigned short* __restrict__ es2w, const float* __restrict__ es2b,
    const unsigned short* __restrict__ rf1w, const float* __restrict__ rf1b,
    const unsigned short* __restrict__ rf2w, const float* __restrict__ rf2b,
    const unsigned short* __restrict__ rf3w, const float* __restrict__ rf3b,
    const float* __restrict__ ps1w,          const float* __restrict__ ps1b,
    const unsigned short* __restrict__ ps2w, const float* __restrict__ ps2b,
    const float* __restrict__ gw,            const float* __restrict__ gb,
    const unsigned short* __restrict__ xs1w, const float* __restrict__ xs1b,
    const unsigned short* __restrict__ xs2w, const float* __restrict__ xs2b,
    const float* __restrict__ xfw,           const float* __restrict__ xfb,
    float* __restrict__ out) {
  __shared__ __align__(16) unsigned short P[2][64 * AST];
  __shared__ __align__(16) unsigned short Q[2][64 * AST];
  __shared__ float probs[2][64 * PST];
  __shared__ float pred_part[2][8 * 64];

  const int t   = threadIdx.x;
  const int r0g = blockIdx.x * 128;   // two 64-row tiles

  // Stage 0: positional encoding -> P[tl] cols [0,64), both tiles.
#pragma unroll
  for (int tl = 0; tl < 2; ++tl) {
    const int row = t & 63, g = t >> 6, c = g & 3, jh = g >> 2;
    const float xv = x[(r0g + tl * 64 + row) * 4 + c];
    float sn[4], cs[4];
#pragma unroll
    for (int jj = 0; jj < 4; jj++) {
      const int j = jh * 4 + jj;
      const float rev = xv * (0.5f * (float)(1 << j));
      sn[jj] = sin_rev(rev);
      cs[jj] = cos_rev(rev);
    }
    uint2 ws; ws.x = pack2(sn[0], sn[1]); ws.y = pack2(sn[2], sn[3]);
    uint2 wc2; wc2.x = pack2(cs[0], cs[1]); wc2.y = pack2(cs[2], cs[3]);
    *(uint2*)(P[tl] + row * AST + c * 16 + jh * 4) = ws;
    *(uint2*)(P[tl] + row * AST + c * 16 + 8 + jh * 4) = wc2;
  }
  __syncthreads();
  wgemm2<64, 1, 0>(P[0], P[1], P[0], P[1], 64, es1w, es1b, nullptr, nullptr);
  __syncthreads();
  wgemm2<128, 2, 0>(P[0] + 64, P[1] + 64, Q[0], Q[1], 0, es2w, es2b, nullptr, nullptr);
  __syncthreads();
  wgemm2<256, 1, 1>(Q[0], Q[1], P[0], P[1], 0, rf1w, rf1b, nullptr, nullptr);
  __syncthreads();
  wgemm2<128, 1, 1>(P[0], P[1], P[0], P[1], 128, rf2w, rf2b, nullptr, nullptr);
  __syncthreads();
  wgemm2<128, 2, 2>(P[0] + 128, P[1] + 128, Q[0], Q[1], 0, rf3w, rf3b, Q[0], Q[1]);
  __syncthreads();
  // pol_s1 (K=4) in f32: pf1 -> P[tl][0,128). 16 outputs/thread/tile.
#pragma unroll
  for (int tl = 0; tl < 2; ++tl) {
    const int row = t & 63, g = t >> 6;
    const v4f xv = *(const v4f*)(x + (r0g + tl * 64 + row) * 4);
#pragma unroll
    for (int ii = 0; ii < 4; ii++) {
      float oo[4];
#pragma unroll
      for (int i2 = 0; i2 < 4; i2++) {
        const int o = g * 16 + ii * 4 + i2;
        const v4f w4 = *(const v4f*)(ps1w + o * 4);
        const float z = xv[0] * w4[0] + xv[1] * w4[1] + xv[2] * w4[2] +
                        xv[3] * w4[3] + ps1b[o];
        oo[i2] = sin_rev(KSIN * z);
      }
      uint2 w2; w2.x = pack2(oo[0], oo[1]); w2.y = pack2(oo[2], oo[3]);
      *(uint2*)(P[tl] + row * AST + g * 16 + ii * 4) = w2;
    }
  }
  __syncthreads();
  wgemm2<128, 1, 0>(P[0], P[1], P[0], P[1], 128, ps2w, ps2b, nullptr, nullptr);
  __syncthreads();
  // gate (f32 weights): per tile, 8 partial-threads per row, 48 k each.
#pragma unroll
  for (int tl = 0; tl < 2; ++tl) {
    const int row = t >> 3, pp = t & 7;
    float lg[7] = {0.f, 0.f, 0.f, 0.f, 0.f, 0.f, 0.f};
#pragma unroll
    for (int u = 0; u < 6; u++) {
      const int kk = pp * 48 + u * 8;
      const v8s av = (kk < 256) ? *(const v8s*)(Q[tl] + row * AST + kk)
                                : *(const v8s*)(P[tl] + row * AST + 128 + (kk - 256));
      float af[8];
#pragma unroll
      for (int e2 = 0; e2 < 8; e2++) af[e2] = bf2f((unsigned short)av[e2]);
#pragma unroll
      for (int j = 0; j < 7; j++) {
        const v4f g0 = *(const v4f*)(gw + j * 384 + kk);
        const v4f g1 = *(const v4f*)(gw + j * 384 + kk + 4);
        lg[j] += af[0] * g0[0] + af[1] * g0[1] + af[2] * g0[2] + af[3] * g0[3] +
                 af[4] * g1[0] + af[5] * g1[1] + af[6] * g1[2] + af[7] * g1[3];
      }
    }
#pragma unroll
    for (int j = 0; j < 7; j++) {
      float s = lg[j];
      s += __shfl_xor(s, 1);
      s += __shfl_xor(s, 2);
      s += __shfl_xor(s, 4);
      lg[j] = s;
    }
    if (pp == 0) {
#pragma unroll
      for (int j = 0; j < 7; j++) probs[tl][row * PST + j] = lg[j] + gb[j];
    }
  }
  __syncthreads();
  float yr = 0.f;
  if (t < 128) {  // softmax over 7, tile = t>>6, row = t&63
    const int tl = t >> 6, row = t & 63;
    float m = probs[tl][row * PST];
#pragma unroll
    for (int j = 1; j < 7; j++) m = fmaxf(m, probs[tl][row * PST + j]);
    float s = 0.f, e[7];
#pragma unroll
    for (int j = 0; j < 7; j++) { e[j] = __expf(probs[tl][row * PST + j] - m); s += e[j]; }
    const float inv = 1.f / s;
#pragma unroll
    for (int j = 0; j < 7; j++) probs[tl][row * PST + j] = e[j] * inv;
  }
  // Q-register-cache: enc_feat a-frags for k0<2, constant across experts.
  v8s qh[2][2][4];   // [tile][k0][rt] = 16 v8s = 64 VGPR
  {
    const int m15 = t & 15, q = (t & 63) >> 4;
#pragma unroll
    for (int k0 = 0; k0 < 2; k0++)
#pragma unroll
      for (int rt = 0; rt < 4; rt++) {
        qh[0][k0][rt] = *(const v8s*)(Q[0] + (rt * 16 + m15) * AST + k0 * 32 + q * 8);
        qh[1][k0][rt] = *(const v8s*)(Q[1] + (rt * 16 + m15) * AST + k0 * 32 + q * 8);
      }
  }
  // experts: enc_feat stays in Q[tl]; e1 -> P[tl]; e2+final fused in regs.
  for (int ex = 0; ex < 7; ++ex) {
    wgemm2q(Q[0], Q[1], P[0], P[1], qh,
            xs1w + ex * 65536, xs1b + ex * 256);
    __syncthreads();
    wexpert2d(P[0], P[1], xs2w + ex * 65536, xs2b + ex * 256, xfw + ex * 256,
              pred_part[0], pred_part[1]);
    __syncthreads();
    if (t < 128) {
      const int tl = t >> 6, row = t & 63;
      float pr = 0.f;
#pragma unroll
      for (int w = 0; w < 8; w++) pr += pred_part[tl][w * 64 + row];
      yr += (pr + xfb[ex]) * probs[tl][row * PST + ex];
    }
  }
  if (t < 128) out[r0g + t] = yr;
}

extern "C" void kernel_launch(void* const* d_in, const int* in_sizes, int n_in,
                              void* d_out, int out_size, void* d_ws, size_t ws_size,
                              hipStream_t stream) {
  (void)out_size; (void)n_in; (void)ws_size;
  const int   idx[N_CVT] = {1, 3, 5, 7, 9, 13, 17, 19};
  // KSIN folded into sine-layer weights (enc_s1, enc_s2, pol_s2, exp_s1, exp_s2)
  const float scl[N_CVT] = {KSIN, KSIN, 1.f, 1.f, 1.f, KSIN, KSIN, KSIN};
  unsigned off[N_CVT], cur = 0;
  CvtArgs a;
  for (int i = 0; i < N_CVT; i++) {
    off[i] = cur;
    a.src[i] = (const float*)d_in[idx[i]];
    a.off[i] = cur;
    a.n[i]   = (unsigned)in_sizes[idx[i]];
    a.scl[i] = scl[i];
    cur += ((unsigned)in_sizes[idx[i]] + 7u) & ~7u;  // 16B-align each array
  }
  unsigned short* dst = (unsigned short*)d_ws;
  hipLaunchKernelGGL(convert_kernel, dim3(1024), dim3(256), 0, stream, a, dst);
  hipLaunchKernelGGL(moe_inr_kernel, dim3(65536 / 128), dim3(512), 0, stream,
      (const float*)d_in[0],
      dst + off[0], (const float*)d_in[2],
      dst + off[1], (const float*)d_in[4],
      dst + off[2], (const float*)d_in[6],
      dst + off[3], (const float*)d_in[8],
      dst + off[4], (const float*)d_in[10],
      (const float*)d_in[11], (const float*)d_in[12],
      dst + off[5], (const float*)d_in[14],
      (const float*)d_in[15], (const float*)d_in[16],
      dst + off[6], (const float*)d_in[18],
      dst + off[7], (const float*)d_in[20],
      (const float*)d_in[21], (const float*)d_in[22],
      (float*)d_out);
}

// Round 14
// 320.932 us; speedup vs baseline: 1.3504x; 1.0276x over previous
//
#include <hip/hip_runtime.h>

// MoE-INR fused megakernel, bf16 MFMA (gfx950).
// Round 18: software-pipelined expert loop on the r15 base (248us best).
// r17 verdict: LDS a-reads NOT on critical path (conflicts -7%, time flat) --
// qh hoist dropped. The only mechanism that has never failed: consolidating
// independent work per barrier section (r13 +27%, r15 +9%). Expert loop was
// e1 -> bar -> e2 -> bar (one GEMM per section). Now: e1 is split into MFMA
// (registers only, reads Q+globalW) and epilogue (P-write); each heavy
// section runs {e2[ex] (reads P) || e1_mfma[ex+1] (reads Q)} = 256 MFMAs,
// two independent dep chains; short section does e1_epi->P + yr update.
// Same 2 barriers/expert. Peak regs ~200 of 256 budget ((512,2), reg model
// r7-r10). Spill signature pre-registered: WRITE_SIZE >10MB -> revert.
// Kept: fused dual-tile wgemm2 (r15), 1x8 wave grid (r12), sin_rev + KSIN
// pre-scale (r9/r11), manual-RNE pack (r8), register-light gate (r6),
// atomic-free expert partials, convert grid 1024.

typedef short v8s __attribute__((ext_vector_type(8)));
typedef float v4f __attribute__((ext_vector_type(4)));

#define KSIN 4.774648293f   // 30/(2*pi): sine-layer scale, folded into weights
#define AST 264             // LDS row stride in bf16 elements (16B-aligned rows)
#define PST 9               // probs row stride (floats)
#define N_CVT 8

__device__ __forceinline__ float bf2f(unsigned short h) {
  union { unsigned u; float f; } v; v.u = ((unsigned)h) << 16; return v.f;
}
__device__ __forceinline__ unsigned short f2bf(float f) {
  union { float f; unsigned u; } v; v.f = f;
  unsigned r = v.u + 0x7fffu + ((v.u >> 16) & 1u);  // RNE
  return (unsigned short)(r >> 16);
}
__device__ __forceinline__ unsigned pack2(float a, float b) {
  return (unsigned)f2bf(a) | ((unsigned)f2bf(b) << 16);  // manual RNE (verified)
}
__device__ __forceinline__ float sin_rev(float x) {  // sin(2*pi*x)
  return __builtin_amdgcn_sinf(x);
}
__device__ __forceinline__ float cos_rev(float x) {  // cos(2*pi*x)
  return __builtin_amdgcn_cosf(x);
}

struct CvtArgs {
  const float* src[N_CVT];
  unsigned     off[N_CVT];
  unsigned     n[N_CVT];
  float        scl[N_CVT];   // KSIN for sine-layer weights, 1.0 otherwise
};

__global__ void convert_kernel(CvtArgs a, unsigned short* __restrict__ dst) {
  const int tid = blockIdx.x * blockDim.x + threadIdx.x;
  const int stride = gridDim.x * blockDim.x;
  for (int k = 0; k < N_CVT; k++) {
    const unsigned n4 = a.n[k] >> 2;
    const float4* s = (const float4*)a.src[k];
    const float sc = a.scl[k];
    uint2* d = (uint2*)(dst + a.off[k]);
    for (unsigned i = tid; i < n4; i += stride) {
      float4 v = s[i];
      uint2 o; o.x = pack2(v.x * sc, v.y * sc); o.y = pack2(v.z * sc, v.w * sc);
      d[i] = o;
    }
    for (unsigned i = (n4 << 2) + tid; i < a.n[k]; i += stride)
      dst[a.off[k] + i] = f2bf(a.src[k][i] * sc);
  }
}

// ------------- fused dual-tile wave GEMM, 1x8 wave grid, RT=4 -------------
// Wave w computes O{0,1}[0:64, oc + w*NPW*16 : +NPW*16] for both tiles.
// b[ct] loaded ONCE per k0, feeds both tiles' MFMAs.
// Swapped operands: lane holds D[wcol=q*4+r][act_row=m15]; packed 8B stores.
// ACT: 0 = sin(2pi*(z + KSIN*b)) [W pre-scaled], 1 = relu, 2 = relu(z+skip)
template<int K, int NPW, int ACT>
__device__ __forceinline__ void wgemm2(const unsigned short* A0,
                                       const unsigned short* A1,
                                       unsigned short* O0, unsigned short* O1,
                                       int oc,
                                       const unsigned short* __restrict__ W,
                                       const float* __restrict__ bias,
                                       const unsigned short* skip0,
                                       const unsigned short* skip1) {
  const int lane = threadIdx.x & 63;
  const int wave = threadIdx.x >> 6;
  const int m15  = lane & 15;
  const int q    = lane >> 4;
  const int n0   = wave * (NPW * 16);
  v4f acc[2][NPW][4];
#pragma unroll
  for (int tl = 0; tl < 2; tl++)
#pragma unroll
    for (int i = 0; i < NPW; i++)
#pragma unroll
      for (int j = 0; j < 4; j++) acc[tl][i][j] = (v4f){0.f, 0.f, 0.f, 0.f};

#pragma unroll
  for (int k0 = 0; k0 < K / 32; ++k0) {
    v8s b[NPW], a0[4], a1[4];
#pragma unroll
    for (int ct = 0; ct < NPW; ct++)
      b[ct] = *(const v8s*)(W + (size_t)(n0 + ct * 16 + m15) * K + k0 * 32 + q * 8);
#pragma unroll
    for (int rt = 0; rt < 4; rt++) {
      a0[rt] = *(const v8s*)(A0 + (rt * 16 + m15) * AST + k0 * 32 + q * 8);
      a1[rt] = *(const v8s*)(A1 + (rt * 16 + m15) * AST + k0 * 32 + q * 8);
    }
#pragma unroll
    for (int ct = 0; ct < NPW; ct++)
#pragma unroll
      for (int rt = 0; rt < 4; rt++) {
        acc[0][ct][rt] = __builtin_amdgcn_mfma_f32_16x16x32_bf16(b[ct], a0[rt], acc[0][ct][rt], 0, 0, 0);
        acc[1][ct][rt] = __builtin_amdgcn_mfma_f32_16x16x32_bf16(b[ct], a1[rt], acc[1][ct][rt], 0, 0, 0);
      }
  }

#pragma unroll
  for (int ct = 0; ct < NPW; ct++) {
    const int c0 = n0 + ct * 16 + q * 4;
    v4f bv = *(const v4f*)(bias + c0);
    if (ACT == 0) bv *= KSIN;
#pragma unroll
    for (int rt = 0; rt < 4; rt++) {
      const int row = rt * 16 + m15;
#pragma unroll
      for (int tl = 0; tl < 2; tl++) {
        const v4f av = acc[tl][ct][rt];
        unsigned short* OUT = tl ? O1 : O0;
        const unsigned short* skip = tl ? skip1 : skip0;
        float o0, o1, o2, o3;
        if (ACT == 2) {
          const uint2 sk = *(const uint2*)(skip + row * AST + c0);
          o0 = fmaxf(av[0] + bv[0] + bf2f((unsigned short)(sk.x & 0xffffu)), 0.f);
          o1 = fmaxf(av[1] + bv[1] + bf2f((unsigned short)(sk.x >> 16)), 0.f);
          o2 = fmaxf(av[2] + bv[2] + bf2f((unsigned short)(sk.y & 0xffffu)), 0.f);
          o3 = fmaxf(av[3] + bv[3] + bf2f((unsigned short)(sk.y >> 16)), 0.f);
        } else if (ACT == 1) {
          o0 = fmaxf(av[0] + bv[0], 0.f);
          o1 = fmaxf(av[1] + bv[1], 0.f);
          o2 = fmaxf(av[2] + bv[2], 0.f);
          o3 = fmaxf(av[3] + bv[3], 0.f);
        } else {
          o0 = sin_rev(av[0] + bv[0]);
          o1 = sin_rev(av[1] + bv[1]);
          o2 = sin_rev(av[2] + bv[2]);
          o3 = sin_rev(av[3] + bv[3]);
        }
        uint2 w2; w2.x = pack2(o0, o1); w2.y = pack2(o2, o3);
        *(uint2*)(OUT + row * AST + oc + c0) = w2;
      }
    }
  }
}

// Expert e1 MFMA only (K=256, NPW=2): acc stays in registers. Reads Q + W.
__device__ __forceinline__ void e1_mfma(const unsigned short* A0,
                                        const unsigned short* A1,
                                        const unsigned short* __restrict__ W,
                                        v4f (&acc)[2][2][4]) {
  const int lane = threadIdx.x & 63;
  const int wave = threadIdx.x >> 6;
  const int m15  = lane & 15;
  const int q    = lane >> 4;
  const int n0   = wave * 32;
#pragma unroll
  for (int tl = 0; tl < 2; tl++)
#pragma unroll
    for (int i = 0; i < 2; i++)
#pragma unroll
      for (int j = 0; j < 4; j++) acc[tl][i][j] = (v4f){0.f, 0.f, 0.f, 0.f};

#pragma unroll
  for (int k0 = 0; k0 < 8; ++k0) {
    v8s b[2], a0[4], a1[4];
#pragma unroll
    for (int ct = 0; ct < 2; ct++)
      b[ct] = *(const v8s*)(W + (size_t)(n0 + ct * 16 + m15) * 256 + k0 * 32 + q * 8);
#pragma unroll
    for (int rt = 0; rt < 4; rt++) {
      a0[rt] = *(const v8s*)(A0 + (rt * 16 + m15) * AST + k0 * 32 + q * 8);
      a1[rt] = *(const v8s*)(A1 + (rt * 16 + m15) * AST + k0 * 32 + q * 8);
    }
#pragma unroll
    for (int ct = 0; ct < 2; ct++)
#pragma unroll
      for (int rt = 0; rt < 4; rt++) {
        acc[0][ct][rt] = __builtin_amdgcn_mfma_f32_16x16x32_bf16(b[ct], a0[rt], acc[0][ct][rt], 0, 0, 0);
        acc[1][ct][rt] = __builtin_amdgcn_mfma_f32_16x16x32_bf16(b[ct], a1[rt], acc[1][ct][rt], 0, 0, 0);
      }
  }
}

// Expert e1 epilogue: sin + pack + P-write from registers.
__device__ __forceinline__ void e1_epi(const v4f (&acc)[2][2][4],
                                       const float* __restrict__ bias,
                                       unsigned short* O0, unsigned short* O1) {
  const int lane = threadIdx.x & 63;
  const int wave = threadIdx.x >> 6;
  const int m15  = lane & 15;
  const int q    = lane >> 4;
  const int n0   = wave * 32;
#pragma unroll
  for (int ct = 0; ct < 2; ct++) {
    const int c0 = n0 + ct * 16 + q * 4;
    v4f bv = *(const v4f*)(bias + c0);
    bv *= KSIN;
#pragma unroll
    for (int rt = 0; rt < 4; rt++) {
      const int row = rt * 16 + m15;
#pragma unroll
      for (int tl = 0; tl < 2; tl++) {
        const v4f av = acc[tl][ct][rt];
        unsigned short* OUT = tl ? O1 : O0;
        float o0 = sin_rev(av[0] + bv[0]);
        float o1 = sin_rev(av[1] + bv[1]);
        float o2 = sin_rev(av[2] + bv[2]);
        float o3 = sin_rev(av[3] + bv[3]);
        uint2 w2; w2.x = pack2(o0, o1); w2.y = pack2(o2, o3);
        *(uint2*)(OUT + row * AST + c0) = w2;
      }
    }
  }
}

// Fused dual-tile expert layer 2 (sine, W pre-scaled) + final 256->1 dot.
// Wave owns 32 unique cols; b loaded once per k0 for both tiles.
// Per-row partial sums -> pp{0,1}[wave][row] (no atomics).
__device__ __forceinline__ void wexpert2d(const unsigned short* A0,
                                          const unsigned short* A1,
                                          const unsigned short* __restrict__ W,
                                          const float* __restrict__ bias,
                                          const float* __restrict__ wfin,
                                          float* __restrict__ pp0,
                                          float* __restrict__ pp1) {
  const int lane = threadIdx.x & 63;
  const int wave = threadIdx.x >> 6;
  const int m15  = lane & 15;
  const int q    = lane >> 4;
  const int n0   = wave * 32;
  v4f acc[2][2][4];
#pragma unroll
  for (int tl = 0; tl < 2; tl++)
#pragma unroll
    for (int i = 0; i < 2; i++)
#pragma unroll
      for (int j = 0; j < 4; j++) acc[tl][i][j] = (v4f){0.f, 0.f, 0.f, 0.f};

#pragma unroll
  for (int k0 = 0; k0 < 8; ++k0) {
    v8s b[2], a0[4], a1[4];
#pragma unroll
    for (int ct = 0; ct < 2; ct++)
      b[ct] = *(const v8s*)(W + (size_t)(n0 + ct * 16 + m15) * 256 + k0 * 32 + q * 8);
#pragma unroll
    for (int rt = 0; rt < 4; rt++) {
      a0[rt] = *(const v8s*)(A0 + (rt * 16 + m15) * AST + k0 * 32 + q * 8);
      a1[rt] = *(const v8s*)(A1 + (rt * 16 + m15) * AST + k0 * 32 + q * 8);
    }
#pragma unroll
    for (int ct = 0; ct < 2; ct++)
#pragma unroll
      for (int rt = 0; rt < 4; rt++) {
        acc[0][ct][rt] = __builtin_amdgcn_mfma_f32_16x16x32_bf16(b[ct], a0[rt], acc[0][ct][rt], 0, 0, 0);
        acc[1][ct][rt] = __builtin_amdgcn_mfma_f32_16x16x32_bf16(b[ct], a1[rt], acc[1][ct][rt], 0, 0, 0);
      }
  }

  float p0[4] = {0.f, 0.f, 0.f, 0.f};
  float p1[4] = {0.f, 0.f, 0.f, 0.f};
#pragma unroll
  for (int ct = 0; ct < 2; ct++) {
    const int c0 = n0 + ct * 16 + q * 4;
    v4f bv = *(const v4f*)(bias + c0);
    bv *= KSIN;
    const v4f wf = *(const v4f*)(wfin + c0);
#pragma unroll
    for (int rt = 0; rt < 4; rt++)
#pragma unroll
      for (int r = 0; r < 4; r++) {
        p0[rt] += sin_rev(acc[0][ct][rt][r] + bv[r]) * wf[r];
        p1[rt] += sin_rev(acc[1][ct][rt][r] + bv[r]) * wf[r];
      }
  }
  // reduce over q (lanes 16 apart hold same act_row, different cols)
#pragma unroll
  for (int rt = 0; rt < 4; rt++) {
    float v0 = p0[rt], v1 = p1[rt];
    v0 += __shfl_xor(v0, 16);
    v0 += __shfl_xor(v0, 32);
    v1 += __shfl_xor(v1, 16);
    v1 += __shfl_xor(v1, 32);
    if (q == 0) {
      pp0[wave * 64 + rt * 16 + m15] = v0;
      pp1[wave * 64 + rt * 16 + m15] = v1;
    }
  }
}

__global__ __launch_bounds__(512, 2) void moe_inr_kernel(
    const float* __restrict__ x,
    const unsigned short* __restrict__ es1w, const float* __restrict__ es1b,
    const unsigned short* __restrict__ es2w, const float* __restrict__ es2b,
    const unsigned short* __restrict__ rf1w, const float* __restrict__ rf1b,
    const unsigned short* __restrict__ rf2w, const float* __restrict__ rf2b,
    const unsigned short* __restrict__ rf3w, const float* __restrict__ rf3b,
    const float* __restrict__ ps1w,          const float* __restrict__ ps1b,
    const unsigned short* __restrict__ ps2w, const float* __restrict__ ps2b,
    const float* __restrict__ gw,            const float* __restrict__ gb,
    const unsigned short* __restrict__ xs1w, const float* __restrict__ xs1b,
    const unsigned short* __restrict__ xs2w, const float* __restrict__ xs2b,
    const float* __restrict__ xfw,           const float* __restrict__ xfb,
    float* __restrict__ out) {
  __shared__ __align__(16) unsigned short P[2][64 * AST];
  __shared__ __align__(16) unsigned short Q[2][64 * AST];
  __shared__ float probs[2][64 * PST];
  __shared__ float pred_part[2][8 * 64];

  const int t   = threadIdx.x;
  const int r0g = blockIdx.x * 128;   // two 64-row tiles

  // Stage 0: positional encoding -> P[tl] cols [0,64), both tiles.
#pragma unroll
  for (int tl = 0; tl < 2; ++tl) {
    const int row = t & 63, g = t >> 6, c = g & 3, jh = g >> 2;
    const float xv = x[(r0g + tl * 64 + row) * 4 + c];
    float sn[4], cs[4];
#pragma unroll
    for (int jj = 0; jj < 4; jj++) {
      const int j = jh * 4 + jj;
      const float rev = xv * (0.5f * (float)(1 << j));
      sn[jj] = sin_rev(rev);
      cs[jj] = cos_rev(rev);
    }
    uint2 ws; ws.x = pack2(sn[0], sn[1]); ws.y = pack2(sn[2], sn[3]);
    uint2 wc2; wc2.x = pack2(cs[0], cs[1]); wc2.y = pack2(cs[2], cs[3]);
    *(uint2*)(P[tl] + row * AST + c * 16 + jh * 4) = ws;
    *(uint2*)(P[tl] + row * AST + c * 16 + 8 + jh * 4) = wc2;
  }
  __syncthreads();
  wgemm2<64, 1, 0>(P[0], P[1], P[0], P[1], 64, es1w, es1b, nullptr, nullptr);
  __syncthreads();
  wgemm2<128, 2, 0>(P[0] + 64, P[1] + 64, Q[0], Q[1], 0, es2w, es2b, nullptr, nullptr);
  __syncthreads();
  wgemm2<256, 1, 1>(Q[0], Q[1], P[0], P[1], 0, rf1w, rf1b, nullptr, nullptr);
  __syncthreads();
  wgemm2<128, 1, 1>(P[0], P[1], P[0], P[1], 128, rf2w, rf2b, nullptr, nullptr);
  __syncthreads();
  wgemm2<128, 2, 2>(P[0] + 128, P[1] + 128, Q[0], Q[1], 0, rf3w, rf3b, Q[0], Q[1]);
  __syncthreads();
  // pol_s1 (K=4) in f32: pf1 -> P[tl][0,128). 16 outputs/thread/tile.
#pragma unroll
  for (int tl = 0; tl < 2; ++tl) {
    const int row = t & 63, g = t >> 6;
    const v4f xv = *(const v4f*)(x + (r0g + tl * 64 + row) * 4);
#pragma unroll
    for (int ii = 0; ii < 4; ii++) {
      float oo[4];
#pragma unroll
      for (int i2 = 0; i2 < 4; i2++) {
        const int o = g * 16 + ii * 4 + i2;
        const v4f w4 = *(const v4f*)(ps1w + o * 4);
        const float z = xv[0] * w4[0] + xv[1] * w4[1] + xv[2] * w4[2] +
                        xv[3] * w4[3] + ps1b[o];
        oo[i2] = sin_rev(KSIN * z);
      }
      uint2 w2; w2.x = pack2(oo[0], oo[1]); w2.y = pack2(oo[2], oo[3]);
      *(uint2*)(P[tl] + row * AST + g * 16 + ii * 4) = w2;
    }
  }
  __syncthreads();
  wgemm2<128, 1, 0>(P[0], P[1], P[0], P[1], 128, ps2w, ps2b, nullptr, nullptr);
  __syncthreads();
  // gate (f32 weights): per tile, 8 partial-threads per row, 48 k each.
#pragma unroll
  for (int tl = 0; tl < 2; ++tl) {
    const int row = t >> 3, pp = t & 7;
    float lg[7] = {0.f, 0.f, 0.f, 0.f, 0.f, 0.f, 0.f};
#pragma unroll
    for (int u = 0; u < 6; u++) {
      const int kk = pp * 48 + u * 8;
      const v8s av = (kk < 256) ? *(const v8s*)(Q[tl] + row * AST + kk)
                                : *(const v8s*)(P[tl] + row * AST + 128 + (kk - 256));
      float af[8];
#pragma unroll
      for (int e2 = 0; e2 < 8; e2++) af[e2] = bf2f((unsigned short)av[e2]);
#pragma unroll
      for (int j = 0; j < 7; j++) {
        const v4f g0 = *(const v4f*)(gw + j * 384 + kk);
        const v4f g1 = *(const v4f*)(gw + j * 384 + kk + 4);
        lg[j] += af[0] * g0[0] + af[1] * g0[1] + af[2] * g0[2] + af[3] * g0[3] +
                 af[4] * g1[0] + af[5] * g1[1] + af[6] * g1[2] + af[7] * g1[3];
      }
    }
#pragma unroll
    for (int j = 0; j < 7; j++) {
      float s = lg[j];
      s += __shfl_xor(s, 1);
      s += __shfl_xor(s, 2);
      s += __shfl_xor(s, 4);
      lg[j] = s;
    }
    if (pp == 0) {
#pragma unroll
      for (int j = 0; j < 7; j++) probs[tl][row * PST + j] = lg[j] + gb[j];
    }
  }
  __syncthreads();
  // Section S0: softmax (t<128, register/probs only) + e1[0] MFMA (reads Q)
  // + e1[0] epilogue -> P. Gate finished reading P at the barrier above.
  float yr = 0.f;
  v4f acc1[2][2][4];
  e1_mfma(Q[0], Q[1], xs1w, acc1);
  if (t < 128) {  // softmax over 7, tile = t>>6, row = t&63
    const int tl = t >> 6, row = t & 63;
    float m = probs[tl][row * PST];
#pragma unroll
    for (int j = 1; j < 7; j++) m = fmaxf(m, probs[tl][row * PST + j]);
    float s = 0.f, e[7];
#pragma unroll
    for (int j = 0; j < 7; j++) { e[j] = __expf(probs[tl][row * PST + j] - m); s += e[j]; }
    const float inv = 1.f / s;
#pragma unroll
    for (int j = 0; j < 7; j++) probs[tl][row * PST + j] = e[j] * inv;
  }
  e1_epi(acc1, xs1b, P[0], P[1]);
  __syncthreads();
  // Pipelined expert loop: {e2[ex] || e1_mfma[ex+1]} -> bar ->
  // {e1_epi[ex+1] -> P ; yr += pred} -> bar.
  for (int ex = 0; ex < 7; ++ex) {
    wexpert2d(P[0], P[1], xs2w + ex * 65536, xs2b + ex * 256, xfw + ex * 256,
              pred_part[0], pred_part[1]);
    if (ex < 6) e1_mfma(Q[0], Q[1], xs1w + (ex + 1) * 65536, acc1);
    __syncthreads();
    if (ex < 6) e1_epi(acc1, xs1b + (ex + 1) * 256, P[0], P[1]);
    if (t < 128) {
      const int tl = t >> 6, row = t & 63;
      float pr = 0.f;
#pragma unroll
      for (int w = 0; w < 8; w++) pr += pred_part[tl][w * 64 + row];
      yr += (pr + xfb[ex]) * probs[tl][row * PST + ex];
    }
    if (ex < 6) __syncthreads();
  }
  if (t < 128) out[r0g + t] = yr;
}

extern "C" void kernel_launch(void* const* d_in, const int* in_sizes, int n_in,
                              void* d_out, int out_size, void* d_ws, size_t ws_size,
                              hipStream_t stream) {
  (void)out_size; (void)n_in; (void)ws_size;
  const int   idx[N_CVT] = {1, 3, 5, 7, 9, 13, 17, 19};
  // KSIN folded into sine-layer weights (enc_s1, enc_s2, pol_s2, exp_s1, exp_s2)
  const float scl[N_CVT] = {KSIN, KSIN, 1.f, 1.f, 1.f, KSIN, KSIN, KSIN};
  unsigned off[N_CVT], cur = 0;
  CvtArgs a;
  for (int i = 0; i < N_CVT; i++) {
    off[i] = cur;
    a.src[i] = (const float*)d_in[idx[i]];
    a.off[i] = cur;
    a.n[i]   = (unsigned)in_sizes[idx[i]];
    a.scl[i] = scl[i];
    cur += ((unsigned)in_sizes[idx[i]] + 7u) & ~7u;  // 16B-align each array
  }
  unsigned short* dst = (unsigned short*)d_ws;
  hipLaunchKernelGGL(convert_kernel, dim3(1024), dim3(256), 0, stream, a, dst);
  hipLaunchKernelGGL(moe_inr_kernel, dim3(65536 / 128), dim3(512), 0, stream,
      (const float*)d_in[0],
      dst + off[0], (const float*)d_in[2],
      dst + off[1], (const float*)d_in[4],
      dst + off[2], (const float*)d_in[6],
      dst + off[3], (const float*)d_in[8],
      dst + off[4], (const float*)d_in[10],
      (const float*)d_in[11], (const float*)d_in[12],
      dst + off[5], (const float*)d_in[14],
      (const float*)d_in[15], (const float*)d_in[16],
      dst + off[6], (const float*)d_in[18],
      dst + off[7], (const float*)d_in[20],
      (const float*)d_in[21], (const float*)d_in[22],
      (float*)d_out);
}